// Round 1
// baseline (322.803 us; speedup 1.0000x reference)
//
#include <hip/hip_runtime.h>

// BlockSample: out[(b*H+y)*W+x, ch, i, j] = in[b, ch, y+i-3, x+j-2] (zero pad),
// with taps (i==3, j>=2) masked to zero.
// Pure data movement: 226.5 MB write + 14.2 MB read -> write-BW bound (~38 us floor).

#define BB 8
#define CC 192
#define HH 48
#define WW 48
// one float4 per (pixel, ch, i): total float4 stores
#define TOTAL4 (BB * HH * WW * CC * 4)   // 14,155,776

__global__ __launch_bounds__(256) void
blocksample_kernel(const float* __restrict__ in, float* __restrict__ out) {
    const int idx4 = blockIdx.x * 256 + threadIdx.x;   // < TOTAL4 (exact multiple)

    const int i   = idx4 & 3;          // tap row 0..3
    const int t   = idx4 >> 2;         // (pix * C + ch)
    const int ch  = t % CC;
    const int pix = t / CC;            // (b*H + y)*W + x
    const int x   = pix % WW;
    const int r2  = pix / WW;
    const int y   = r2 % HH;
    const int b   = r2 / HH;

    const int row = y + i - 3;         // input row for this tap row
    float4 v = make_float4(0.f, 0.f, 0.f, 0.f);

    if (row >= 0 && row < HH) {
        const float* rp = in + ((((b * CC + ch) * HH) + row) * WW);
        const int c0 = x - 2;          // col for j=0
        if (c0 >= 0 && c0 + 3 < WW) {
            // interior fast path: 4 contiguous scalar loads (unaligned base)
            v.x = rp[c0 + 0];
            v.y = rp[c0 + 1];
            v.z = rp[c0 + 2];
            v.w = rp[c0 + 3];
        } else {
            // boundary: per-element predicates (x==0,1 left edge; x==47 right edge)
            if (c0 + 0 >= 0)            v.x = rp[c0 + 0];   // c0 < WW always (x-2 <= 45)
            if (c0 + 1 >= 0)            v.y = rp[c0 + 1];   // c0+1 <= 46 < WW always
            /* c0+2 == x: always in [0,WW) */ v.z = rp[c0 + 2];
            if (c0 + 3 < WW)            v.w = rp[c0 + 3];   // c0+3 = x+1 >= 1 always
        }
    }

    // masked taps: (i==3, j==2) and (i==3, j==3)
    if (i == 3) { v.z = 0.f; v.w = 0.f; }

    reinterpret_cast<float4*>(out)[idx4] = v;
}

extern "C" void kernel_launch(void* const* d_in, const int* in_sizes, int n_in,
                              void* d_out, int out_size, void* d_ws, size_t ws_size,
                              hipStream_t stream) {
    const float* in = (const float*)d_in[0];
    float* out = (float*)d_out;
    blocksample_kernel<<<dim3(TOTAL4 / 256), dim3(256), 0, stream>>>(in, out);
}

// Round 4
// 250.731 us; speedup vs baseline: 1.2874x; 1.2874x over previous
//
#include <hip/hip_runtime.h>

// BlockSample: out[(b*H+y)*W+x, ch, i, j] = in[b, ch, y+i-3, x+j-2] (zero pad),
// taps (i==3, j>=2) masked to zero.
//
// R1 lesson: per-thread scattered reads (64 distinct lines per load instr) made
// the kernel TA-request-rate bound (1.9 TB/s, FETCH 4x over-fetch).
// R2/R3: stage input rows via LDS with coalesced reads; writes stay
// 1KB-contiguous float4 per wave; odd LDS pitch (55) -> 2-way bank aliasing
// only (free); XCD swizzle so y-adjacent blocks (sharing 3/4 rows) hit the
// same L2; nontemporal stores keep the 226 MB write stream out of L2.
// R4 fix: output float4 pixel stride is CC*4 (=768), not CC — R3 dropped the
// factor 4 in the store addressing.

#define BB 8
#define CC 192
#define HH 48
#define WW 48
#define G  16                  // channels per block
#define NCHG (CC / G)          // 12
#define PITCH 55               // LDS row pitch (odd -> conflict-free)
#define NBLK (BB * NCHG * HH)  // 4608 blocks
#define NXCD 8

typedef float vfloat4 __attribute__((ext_vector_type(4)));

__global__ __launch_bounds__(256) void
blocksample_kernel(const float* __restrict__ in, float* __restrict__ out) {
    // XCD-aware swizzle: blockIdx % 8 ~ XCD. Give each XCD a contiguous span of
    // (b, chg, y) space with y fastest so y,y+1 (sharing 3 rows) reuse L2.
    const int id    = blockIdx.x;
    const int xcd   = id & (NXCD - 1);
    const int local = id >> 3;                    // 0 .. NBLK/8-1
    const int g     = xcd * (NBLK / NXCD) + local;

    const int y   = g % HH;
    const int chg = (g / HH) % NCHG;
    const int b   = g / (HH * NCHG);

    __shared__ float lds[G * 4 * PITCH];          // 16ch x 4rows x 55 = 14,080 B

    const int t = threadIdx.x;

    // 1) zero LDS (covers padding cols + out-of-bounds rows)
    for (int k = t; k < G * 4 * PITCH; k += 256) lds[k] = 0.0f;
    __syncthreads();

    // 2) fill: 64 (ch,row) pairs x 48 cols, coalesced 48-float row reads.
    //    lds[(ch*4+i)*PITCH + 3 + col] = in[b, chg*G+ch, y+i-3, col]
    const float* inb = in + ((size_t)(b * CC + chg * G) * HH) * WW;
    for (int f = t; f < G * 4 * WW; f += 256) {
        const int rc  = f / WW;                   // (ch*4 + i), 0..63
        const int col = f - rc * WW;
        const int i   = rc & 3;
        const int ch  = rc >> 2;
        const int row = y + i - 3;
        if (row >= 0 && row < HH) {
            lds[rc * PITCH + 3 + col] = inb[(ch * HH + row) * WW + col];
        }
    }
    __syncthreads();

    // 3) write: wave w handles x = w, w+4, ..., one 1KB contiguous store each.
    //    lane l -> ch_local = l>>2, i = l&3; float4 within pixel = chg*G*4 + l.
    //    Per-pixel stride in float4 units = CC*4 = 768.
    const int w = t >> 6;                         // wave 0..3
    const int l = t & 63;
    const int i = l & 3;
    const float* lrow = lds + l * PITCH;          // (ch_local*4+i)*PITCH == l*PITCH

    vfloat4* outb = (vfloat4*)out
        + ((size_t)((b * HH + y) * WW) * CC + chg * G) * 4 + l;

    for (int x = w; x < WW; x += 4) {
        vfloat4 v;
        const float* p = lrow + (x + 1);          // col x-2 at pad offset 3
        v.x = p[0];
        v.y = p[1];
        v.z = p[2];
        v.w = p[3];
        if (i == 3) { v.z = 0.0f; v.w = 0.0f; }   // masked taps (3,2),(3,3)
        __builtin_nontemporal_store(v, outb + (size_t)x * (CC * 4));
    }
}

extern "C" void kernel_launch(void* const* d_in, const int* in_sizes, int n_in,
                              void* d_out, int out_size, void* d_ws, size_t ws_size,
                              hipStream_t stream) {
    const float* in = (const float*)d_in[0];
    float* out = (float*)d_out;
    blocksample_kernel<<<dim3(NBLK), dim3(256), 0, stream>>>(in, out);
}

// Round 5
// 240.502 us; speedup vs baseline: 1.3422x; 1.0425x over previous
//
#include <hip/hip_runtime.h>

// BlockSample: out[(b*H+y)*W+x, ch, i, j] = in[b, ch, y+i-3, x+j-2] (zero pad),
// taps (i==3, j>=2) masked to zero.
//
// R1: per-thread scattered reads -> TA-request bound (150 us).
// R4: LDS staging + coalesced 1KB/wave float4 NT stores -> ~90-105 us.
// R5 theory: NT (no-allocate) stores bypass L2 and write partial lines ->
// ~2.4 TB/s effective write BW. Harness fill kernel proves plain cached
// stores reach 6.3 TB/s. A/B: drop NT, keep structure. Also zero only the
// LDS halo columns (OOB rows handled by select in the fill loop).

#define BB 8
#define CC 192
#define HH 48
#define WW 48
#define G  16                  // channels per block
#define NCHG (CC / G)          // 12
#define PITCH 55               // LDS row pitch: 3 pad + 48 + 4 spare (odd -> no conflicts)
#define NBLK (BB * NCHG * HH)  // 4608 blocks
#define NXCD 8

typedef float vfloat4 __attribute__((ext_vector_type(4)));

__global__ __launch_bounds__(256) void
blocksample_kernel(const float* __restrict__ in, float* __restrict__ out) {
    // XCD-aware swizzle: y-adjacent blocks (sharing 3/4 input rows) on same XCD.
    const int id    = blockIdx.x;
    const int xcd   = id & (NXCD - 1);
    const int local = id >> 3;
    const int g     = xcd * (NBLK / NXCD) + local;

    const int y   = g % HH;
    const int chg = (g / HH) % NCHG;
    const int b   = g / (HH * NCHG);

    __shared__ float lds[G * 4 * PITCH];          // 16ch x 4rows x 55 = 14,080 B

    const int t = threadIdx.x;

    // 1) zero only the halo columns: per row rc, cols {0,1,2, 51,52,53,54}.
    //    64 rows x 7 cols = 448 words, 2 strided iterations.
    {
        static const int haloCol[7] = {0, 1, 2, 51, 52, 53, 54};
        for (int k = t; k < G * 4 * 7; k += 256) {
            const int rc = k / 7;
            const int hc = k - rc * 7;
            lds[rc * PITCH + haloCol[hc]] = 0.0f;
        }
    }

    // 2) fill interior: lds[(ch*4+i)*PITCH + 3 + col] = in[b, chg*G+ch, y+i-3, col]
    //    (select 0 when input row OOB -> no pre-zeroing of interior needed)
    const float* inb = in + ((size_t)(b * CC + chg * G) * HH) * WW;
    for (int f = t; f < G * 4 * WW; f += 256) {
        const int rc  = f / WW;                   // (ch*4 + i), 0..63
        const int col = f - rc * WW;
        const int i   = rc & 3;
        const int ch  = rc >> 2;
        const int row = y + i - 3;
        float val = 0.0f;
        if (row >= 0 && row < HH) val = inb[(ch * HH + row) * WW + col];
        lds[rc * PITCH + 3 + col] = val;
    }
    __syncthreads();

    // 3) write: wave w handles x = w, w+4, ...; one 1KB-contiguous store per x.
    //    lane l -> (ch_local = l>>2, i = l&3); float4 within pixel = chg*G*4 + l;
    //    per-pixel stride = CC*4 = 768 float4.
    const int w = t >> 6;
    const int l = t & 63;
    const int i = l & 3;
    const float* lrow = lds + l * PITCH;

    vfloat4* outb = (vfloat4*)out
        + ((size_t)((b * HH + y) * WW) * CC + chg * G) * 4 + l;

    for (int x = w; x < WW; x += 4) {
        vfloat4 v;
        const float* p = lrow + (x + 1);          // col x-2 sits at pad offset 3
        v.x = p[0];
        v.y = p[1];
        v.z = p[2];
        v.w = p[3];
        if (i == 3) { v.z = 0.0f; v.w = 0.0f; }   // masked taps (3,2),(3,3)
        outb[(size_t)x * (CC * 4)] = v;           // plain cached store (A/B vs NT)
    }
}

extern "C" void kernel_launch(void* const* d_in, const int* in_sizes, int n_in,
                              void* d_out, int out_size, void* d_ws, size_t ws_size,
                              hipStream_t stream) {
    const float* in = (const float*)d_in[0];
    float* out = (float*)d_out;
    blocksample_kernel<<<dim3(NBLK), dim3(256), 0, stream>>>(in, out);
}

// Round 6
// 225.107 us; speedup vs baseline: 1.4340x; 1.0684x over previous
//
#include <hip/hip_runtime.h>

// BlockSample: out[(b*H+y)*W+x, ch, i, j] = in[b, ch, y+i-3, x+j-2] (zero pad),
// taps (i==3, j>=2) masked to zero.
//
// R1: scattered reads -> TA-bound 150 us. R4/R5: LDS staging + 1KB/wave
// coalesced float4 stores -> ~67 us (write floor ~40 us).
// R6: amortize fill/sync per-block overhead with Y=3 y-tiling: stage 6 rows
// x 16 ch once, emit 3 y's of stores (144 KB/block). Grid 1536 = exactly
// 6 blocks/CU (LDS 21.1 KB x 6 = 127 KB). float4 fill loads. Read traffic
// 56.6 -> 28 MB. LDS pitch 55 (odd): store-phase rowidx=6ch+i covers every
// bank exactly 2x -> conflict-free (2-way is free on gfx950).

#define BB 8
#define CC 192
#define HH 48
#define WW 48
#define G   16                 // channels per block
#define NCHG (CC / G)          // 12
#define YT  3                  // y's per block
#define NYG (HH / YT)          // 16
#define NROW (YT + 3)          // 6 staged rows per channel
#define PITCH 55               // 3 left pad + 48 + 4 spare; odd -> conflict-free
#define NBLK (BB * NCHG * NYG) // 1536 blocks = 6/CU exactly
#define NXCD 8

typedef float vfloat4 __attribute__((ext_vector_type(4)));

__global__ __launch_bounds__(256) void
blocksample_kernel(const float* __restrict__ in, float* __restrict__ out) {
    // XCD swizzle: contiguous (b,chg,yg) span per XCD; yg fastest so adjacent
    // tiles (sharing 3 halo rows) hit the same L2.
    const int id    = blockIdx.x;
    const int xcd   = id & (NXCD - 1);
    const int g     = xcd * (NBLK / NXCD) + (id >> 3);

    const int yg  = g % NYG;
    const int chg = (g / NYG) % NCHG;
    const int b   = g / (NYG * NCHG);
    const int y0  = yg * YT;

    __shared__ float lds[G * NROW * PITCH];       // 16 x 6 x 55 x 4B = 21,120 B

    const int t = threadIdx.x;

    // 1) zero the read halo: cols {1,2,51} of each of the 96 rows.
    //    (store phase reads LDS cols 1..51; fill writes 3..50.)
    for (int k = t; k < G * NROW * 3; k += 256) {
        const int rc = k / 3;
        const int m  = k - rc * 3;
        const int c  = (m == 0) ? 1 : ((m == 1) ? 2 : 51);
        lds[rc * PITCH + c] = 0.0f;
    }

    // 2) fill interior with float4 loads: rc = ch*NROW + dyr covers rows
    //    y0-3 .. y0+2 per channel; OOB rows written as zeros.
    const float* inb = in + ((size_t)(b * CC + chg * G) * HH) * WW;
    for (int f = t; f < G * NROW * (WW / 4); f += 256) {
        const int rc  = f / (WW / 4);             // 0..95
        const int c4  = f - rc * (WW / 4);        // 0..11
        const int ch  = rc / NROW;
        const int dyr = rc - ch * NROW;
        const int row = y0 - 3 + dyr;
        vfloat4 val = (vfloat4)(0.0f);
        if (row >= 0 && row < HH)
            val = *(const vfloat4*)(inb + ((size_t)(ch * HH + row)) * WW + c4 * 4);
        float* dst = lds + rc * PITCH + 3 + c4 * 4;
        dst[0] = val.x; dst[1] = val.y; dst[2] = val.z; dst[3] = val.w;
    }
    __syncthreads();

    // 3) stores: lane l -> (ch = l>>2, i = l&3); wave w covers x = w,w+4,...
    //    LDS row index = ch*NROW + (y-y0) + i ; one 1KB-contiguous store per
    //    (y,x); per-pixel stride = CC*4 = 768 float4.
    const int w  = t >> 6;
    const int l  = t & 63;
    const int i  = l & 3;
    const int ch = l >> 2;
    const float* lbase = lds + (ch * NROW + i) * PITCH;

    vfloat4* outb = (vfloat4*)out
        + ((size_t)((b * HH + y0) * WW) * CC + chg * G) * 4 + l;

    for (int dy = 0; dy < YT; ++dy) {
        const float* lrow = lbase + dy * PITCH;
        vfloat4* orow = outb + (size_t)dy * (WW * CC * 4);
        for (int x = w; x < WW; x += 4) {
            const float* p = lrow + (x + 1);      // input col x-2 at LDS col x+1
            vfloat4 v;
            v.x = p[0];
            v.y = p[1];
            v.z = p[2];
            v.w = p[3];
            if (i == 3) { v.z = 0.0f; v.w = 0.0f; }  // masked taps (3,2),(3,3)
            orow[(size_t)x * (CC * 4)] = v;
        }
    }
}

extern "C" void kernel_launch(void* const* d_in, const int* in_sizes, int n_in,
                              void* d_out, int out_size, void* d_ws, size_t ws_size,
                              hipStream_t stream) {
    const float* in = (const float*)d_in[0];
    float* out = (float*)d_out;
    blocksample_kernel<<<dim3(NBLK), dim3(256), 0, stream>>>(in, out);
}